// Round 11
// baseline (281.554 us; speedup 1.0000x reference)
//
#include <hip/hip_runtime.h>
#include <hip/hip_bf16.h>

typedef unsigned short u16;
typedef __attribute__((ext_vector_type(8))) __bf16 bf16x8;
typedef __attribute__((ext_vector_type(4))) __bf16 bf16x4;
typedef __attribute__((ext_vector_type(4))) float f32x4;

#define AS1 __attribute__((address_space(1)))
#define AS3 __attribute__((address_space(3)))

__device__ inline void gload_lds16(const void* g, void* l) {
  __builtin_amdgcn_global_load_lds((const AS1 void*)g, (AS3 void*)l, 16, 0, 0);
}

__device__ inline u16 f2bf(float f) {
  __bf16 h = (__bf16)f;
  return __builtin_bit_cast(u16, h);
}

// ---------------- fused weight transpose + bf16 convert ----------------
__global__ void conv_weights(const float* __restrict__ W1, const float* __restrict__ W2,
                             const float* __restrict__ W3, u16* __restrict__ w1t,
                             u16* __restrict__ w2t, u16* __restrict__ w3t) {
  int e = blockIdx.x * 256 + threadIdx.x;          // 0 .. 212991
  if (e < 131072) {
    int h = e >> 9, f = e & 511;
    w1t[e] = f2bf(W1[f * 256 + h]);
  } else if (e < 196608) {
    int x = e - 131072;
    int n = x >> 8, k = x & 255;
    w2t[x] = f2bf(W2[k * 256 + n]);
  } else if (e < 212992) {
    int x = e - 196608;
    int n = x >> 8, k = x & 255;
    w3t[x] = f2bf(W3[k * 64 + n]);
  }
}

// ================= mega: scan (streaming) ∥ mlp32 (MFMA) =================
// 10240 blocks, shared 34816 B LDS alloc -> 4 blocks/CU.
// bid%5==4 -> mlp32 block g=bid/5 (2048, rows g*32..+32).
// else     -> scan quarter (bid/5)*4 + bid%5 (8192).
// Rationale: scan is BW-bound (VALU ~13%), mlp is MFMA-bound; a 4:1 resident
// mix overlaps HBM streaming with matrix work. Scan saturation needs only
// ~9.2 KB in flight/CU; 16 float4/thread upfront gives 16 KB/wave.

// ---- scan role: quarter-row stream, candidates -> global ----
__device__ void scan_body(int bid, int t, const float* __restrict__ ppr,
                          float* __restrict__ cv, int* __restrict__ ci,
                          int* __restrict__ cq, float* __restrict__ gs,
                          char* smem) {
  int*   cnt  = (int*)smem;
  float* part = (float*)(smem + 16);
  const int lane = t & 63, wid = t >> 6;
  const int q = bid & 3;
  const float4* rp = (const float4*)(ppr + ((size_t)(bid >> 2) * 65536 + q * 16384));
  const float T0 = 0.997f;
  if (t == 0) *cnt = 0;
  __syncthreads();

  float4 v[16];
#pragma unroll
  for (int i = 0; i < 16; ++i) v[i] = rp[i * 256 + t];

  float sum = 0.f;
  float* cvb = cv + (size_t)bid * 256;
  int*   cib = ci + (size_t)bid * 256;
#pragma unroll
  for (int i = 0; i < 16; ++i) {
    float4 x = v[i];
    sum += (x.x + x.y) + (x.z + x.w);
    float mx = fmaxf(fmaxf(x.x, x.y), fmaxf(x.z, x.w));
    if (mx > T0) {
      float xs[4] = {x.x, x.y, x.z, x.w};
      int fb = q * 16384 + (i * 256 + t) * 4;
#pragma unroll
      for (int j = 0; j < 4; ++j) {
        if (xs[j] > T0) {
          int p = atomicAdd(cnt, 1);
          if (p < 256) { cvb[p] = xs[j]; cib[p] = fb + j; }
        }
      }
    }
  }
#pragma unroll
  for (int off = 32; off > 0; off >>= 1) sum += __shfl_down(sum, off);
  if (lane == 0) part[wid] = sum;
  __syncthreads();
  if (t == 0) {
    gs[bid] = (part[0] + part[1]) + (part[2] + part[3]);
    cq[bid] = *cnt;
  }
}

// ---- mlp32 role: lg[g*32..+32] = relu(relu(X@W1)@W2) @ W3, BM=32 ----
__device__ void mlp32_body(int g, int t, const float* __restrict__ X,
                           const u16* __restrict__ W1t, const u16* __restrict__ W2t,
                           const u16* __restrict__ W3t, float* __restrict__ lg,
                           char* smem) {
  u16* As   = (u16*)smem;                 // [32][32]   2 KB   (phase 1)
  u16* Bs   = (u16*)(smem + 2048);        // [256][32] 16 KB   (phase 1,2)
  u16* h1s  = (u16*)(smem + 18432);       // [32][256] 16 KB swz (phase 1->2)
  u16* quad = (u16*)smem;                 // [32][64]   4 KB swz (phase 3, reuses As/Bs)
  u16* w3s  = (u16*)(smem + 4096);        // [64][64]   8 KB swz (phase 3)
  const int wid = t >> 6, lane = t & 63;
  const int wr = wid >> 1, wc = wid & 1;
  const int l15 = lane & 15, lk = lane >> 4;
  const f32x4 z = {0.f, 0.f, 0.f, 0.f};

  // ---- phase 1: h1s = relu(X @ W1) ----
  {
    f32x4 acc[8];
#pragma unroll
    for (int j = 0; j < 8; ++j) acc[j] = z;

    for (int k0 = 0; k0 < 512; k0 += 32) {
#pragma unroll
      for (int it = 0; it < 4; ++it) {          // W1 tile [256][32]
        int s = it * 256 + t;
        gload_lds16(W1t + (size_t)(s >> 2) * 512 + k0 + (s & 3) * 8,
                    &Bs[(it * 256 + wid * 64) * 8]);
      }
      {                                          // X tile [32][32] fp32->bf16
        int row = t >> 3, cs = (t & 7) * 4;
        float4 v = *(const float4*)(X + (size_t)(g * 32 + row) * 512 + k0 + cs);
        bf16x4 wv;
        wv[0] = (__bf16)v.x; wv[1] = (__bf16)v.y; wv[2] = (__bf16)v.z; wv[3] = (__bf16)v.w;
        *(bf16x4*)&As[row * 32 + cs] = wv;
      }
      __syncthreads();
      bf16x8 af, bfr[8];
      af = *(const bf16x8*)&As[(wr * 16 + l15) * 32 + lk * 8];
#pragma unroll
      for (int j = 0; j < 8; ++j)
        bfr[j] = *(const bf16x8*)&Bs[(wc * 128 + j * 16 + l15) * 32 + lk * 8];
#pragma unroll
      for (int j = 0; j < 8; ++j)
        acc[j] = __builtin_amdgcn_mfma_f32_16x16x32_bf16(af, bfr[j], acc[j], 0, 0, 0);
      __syncthreads();
    }
#pragma unroll
    for (int j = 0; j < 8; ++j)
#pragma unroll
      for (int r = 0; r < 4; ++r) {
        int row = wr * 16 + lk * 4 + r;
        int col = wc * 128 + j * 16 + l15;
        h1s[(row * 256 + col) ^ ((row & 7) << 3)] = f2bf(fmaxf(acc[j][r], 0.f));
      }
    __syncthreads();
  }

  // ---- phase 2: acc2 = h1s @ W2 ----
  f32x4 acc2[8];
#pragma unroll
  for (int j = 0; j < 8; ++j) acc2[j] = z;

  for (int k0 = 0; k0 < 256; k0 += 32) {
#pragma unroll
    for (int it = 0; it < 4; ++it) {            // W2 tile [256][32]
      int s = it * 256 + t;
      gload_lds16(W2t + (size_t)(s >> 2) * 256 + k0 + (s & 3) * 8,
                  &Bs[(it * 256 + wid * 64) * 8]);
    }
    __syncthreads();
    bf16x8 af, bfr[8];
    {
      int row = wr * 16 + l15;
      af = *(const bf16x8*)&h1s[(row * 256 + k0 + lk * 8) ^ ((row & 7) << 3)];
    }
#pragma unroll
    for (int j = 0; j < 8; ++j)
      bfr[j] = *(const bf16x8*)&Bs[(wc * 128 + j * 16 + l15) * 32 + lk * 8];
#pragma unroll
    for (int j = 0; j < 8; ++j)
      acc2[j] = __builtin_amdgcn_mfma_f32_16x16x32_bf16(af, bfr[j], acc2[j], 0, 0, 0);
    __syncthreads();
  }

  // ---- phase 3: lg = relu(acc2) @ W3 via swizzled LDS bounce ----
  f32x4 acc3[2];
#pragma unroll
  for (int j = 0; j < 2; ++j) acc3[j] = z;
  const int rh = wid & 1, cp = wid >> 1;        // rows rh*16..+16, cols cp*32..+32

#pragma unroll
  for (int kk = 0; kk < 4; ++kk) {
    if (wc == (kk >> 1)) {                      // owner waves dump quadrant kk
#pragma unroll
      for (int j4 = 0; j4 < 4; ++j4) {
        int j = (kk & 1) * 4 + j4;
#pragma unroll
        for (int r = 0; r < 4; ++r) {
          int row = wr * 16 + lk * 4 + r;
          int c   = j4 * 16 + l15;
          quad[(row * 64 + c) ^ ((row & 7) << 3)] = f2bf(fmaxf(acc2[j][r], 0.f));
        }
      }
    }
#pragma unroll
    for (int it = 0; it < 2; ++it) {            // W3 chunk, pre-swizzled source
      int s = it * 256 + t;
      int col = s >> 3;
      int koff = ((s ^ (col & 7)) & 7) * 8;
      gload_lds16(W3t + (size_t)col * 256 + kk * 64 + koff, &w3s[(it * 256 + wid * 64) * 8]);
    }
    __syncthreads();
    bf16x8 af2, bfr2[2];
#pragma unroll
    for (int ks = 0; ks < 2; ++ks) {
#pragma unroll
      for (int j2 = 0; j2 < 2; ++j2) {
        int col = cp * 32 + j2 * 16 + l15;
        bfr2[j2] = *(const bf16x8*)&w3s[(col * 64 + ks * 32 + lk * 8) ^ ((col & 7) << 3)];
      }
      {
        int row = rh * 16 + l15;
        af2 = *(const bf16x8*)&quad[(row * 64 + ks * 32 + lk * 8) ^ ((row & 7) << 3)];
      }
#pragma unroll
      for (int j2 = 0; j2 < 2; ++j2)
        acc3[j2] = __builtin_amdgcn_mfma_f32_16x16x32_bf16(af2, bfr2[j2], acc3[j2], 0, 0, 0);
    }
    __syncthreads();
  }

#pragma unroll
  for (int j2 = 0; j2 < 2; ++j2) {
    int col = cp * 32 + j2 * 16 + l15;
#pragma unroll
    for (int r = 0; r < 4; ++r) {
      int row = rh * 16 + lk * 4 + r;
      lg[(size_t)(g * 32 + row) * 64 + col] = acc3[j2][r];
    }
  }
}

__global__ __launch_bounds__(256) void mega(const float* __restrict__ ppr,
                                            float* __restrict__ cv, int* __restrict__ ci,
                                            int* __restrict__ cq, float* __restrict__ gs,
                                            const float* __restrict__ X,
                                            const u16* __restrict__ W1t,
                                            const u16* __restrict__ W2t,
                                            const u16* __restrict__ W3t,
                                            float* __restrict__ lg) {
  __shared__ alignas(16) char smem[34816];
  const int bid = blockIdx.x, t = threadIdx.x;
  const int role = bid % 5, g = bid / 5;
  if (role == 4) mlp32_body(g, t, X, W1t, W2t, W3t, lg, smem);
  else           scan_body(g * 4 + role, t, ppr, cv, ci, cq, gs, smem);
}

// ================= merge + extraction + medoid per row (R10-verified) =================
__global__ __launch_bounds__(256) void merge_medoid(const float* __restrict__ ppr,
                                                    const float* __restrict__ cv,
                                                    const int* __restrict__ ci,
                                                    const int* __restrict__ cq,
                                                    const float* __restrict__ gs,
                                                    const float* __restrict__ lg,
                                                    float* __restrict__ out) {
  __shared__ alignas(16) char smem[13312];
  float* cvals = (float*)smem;              // [1024]
  int*   cidx  = (int*)(smem + 4096);       // [1024]
  float* xk    = (float*)smem;              // [32][65] (phase 3, aliases cands)
  float* l2m   = (float*)(smem + 8448);     // [32][33]
  float* vals  = (float*)(smem + 12672);    // [32]
  int*   idxs  = (int*)(smem + 12800);      // [32]
  float* dist  = (float*)(smem + 12928);    // [32]
  float* wgt   = (float*)(smem + 13056);    // [32]
  float* rsum  = (float*)(smem + 13184);    // [1]

  const int b = blockIdx.x, t = threadIdx.x;
  const int lane = t & 63, wid = t >> 6;
  const float* row = ppr + (size_t)b * 65536;

  const int q0 = cq[b * 4 + 0], q1 = cq[b * 4 + 1], q2 = cq[b * 4 + 2], q3 = cq[b * 4 + 3];
  const int n0 = q0 < 256 ? q0 : 256, n1 = q1 < 256 ? q1 : 256,
            n2 = q2 < 256 ? q2 : 256, n3 = q3 < 256 ? q3 : 256;
  const int o1 = n0, o2 = n0 + n1, o3 = n0 + n1 + n2;
  const int n = o3 + n3;
  const bool ovf = (q0 > 256) | (q1 > 256) | (q2 > 256) | (q3 > 256);

  if (t < n0) { cvals[t]      = cv[(size_t)(b * 4 + 0) * 256 + t]; cidx[t]      = ci[(size_t)(b * 4 + 0) * 256 + t]; }
  if (t < n1) { cvals[o1 + t] = cv[(size_t)(b * 4 + 1) * 256 + t]; cidx[o1 + t] = ci[(size_t)(b * 4 + 1) * 256 + t]; }
  if (t < n2) { cvals[o2 + t] = cv[(size_t)(b * 4 + 2) * 256 + t]; cidx[o2 + t] = ci[(size_t)(b * 4 + 2) * 256 + t]; }
  if (t < n3) { cvals[o3 + t] = cv[(size_t)(b * 4 + 3) * 256 + t]; cidx[o3 + t] = ci[(size_t)(b * 4 + 3) * 256 + t]; }
  if (t == 0)
    *rsum = (gs[b * 4 + 0] + gs[b * 4 + 1]) + (gs[b * 4 + 2] + gs[b * 4 + 3]);
  __syncthreads();

  if (wid == 0) {
    if (n >= 32 && !ovf) {
      for (int r = 0; r < 32; ++r) {
        float bv = -__builtin_inff();
        int bi = 0x7fffffff, bp = -1;
        for (int p = lane; p < n; p += 64) {
          float xv = cvals[p];
          int xi = cidx[p];
          if (xv > bv || (xv == bv && xi < bi)) { bv = xv; bi = xi; bp = p; }
        }
#pragma unroll
        for (int off = 32; off > 0; off >>= 1) {
          float ov = __shfl_down(bv, off);
          int   oi = __shfl_down(bi, off);
          int   op = __shfl_down(bp, off);
          if (ov > bv || (ov == bv && oi < bi)) { bv = ov; bi = oi; bp = op; }
        }
        if (lane == 0) {
          vals[r] = bv; idxs[r] = bi;
          if (bp >= 0) { cvals[bp] = -__builtin_inff(); cidx[bp] = 0x7fffffff; }
        }
      }
    } else {
      // exact fallback (never taken for uniform data)
      for (int r = 0; r < 32; ++r) {
        float bv = -__builtin_inff();
        int bi = 0x7fffffff;
        for (int p = lane; p < 65536; p += 64) {
          float xv = row[p];
          bool skip = false;
          for (int qq = 0; qq < r; ++qq) skip = skip || (idxs[qq] == p);
          if (!skip && (xv > bv || (xv == bv && p < bi))) { bv = xv; bi = p; }
        }
#pragma unroll
        for (int off = 32; off > 0; off >>= 1) {
          float ov = __shfl_down(bv, off);
          int   oi = __shfl_down(bi, off);
          if (ov > bv || (ov == bv && oi < bi)) { bv = ov; bi = oi; }
        }
        if (lane == 0) { vals[r] = bv; idxs[r] = bi; }
      }
    }
  }
  __syncthreads();

  const float rs_b = *rsum;
#pragma unroll
  for (int j = 0; j < 8; ++j) {
    int s = j * 256 + t;
    int r = s >> 6, c = s & 63;
    xk[r * 65 + c] = lg[(size_t)idxs[r] * 64 + c];
  }
  __syncthreads();
#pragma unroll
  for (int j = 0; j < 4; ++j) {
    int p = j * 256 + t;
    int c = p >> 5, m = p & 31;
    float d = 0.f;
#pragma unroll
    for (int ch = 0; ch < 64; ++ch) {
      float df = xk[c * 65 + ch] - xk[m * 65 + ch];
      d += df * df;
    }
    l2m[c * 33 + m] = sqrtf(d + 1e-12f);
  }
  __syncthreads();
  if (t < 32) {
    float d = 0.f;
#pragma unroll
    for (int m = 0; m < 32; ++m) d += vals[m] * l2m[t * 33 + m];
    if (vals[t] == 0.f) d = 3.402823466e+38f;
    dist[t] = d;
  }
  __syncthreads();
  if (t == 0) {
    float mx = -3.402823466e+38f;
    for (int c = 0; c < 32; ++c) mx = fmaxf(mx, -dist[c]);
    float s = 0.f;
    for (int c = 0; c < 32; ++c) { float e = expf(-dist[c] - mx); wgt[c] = e; s += e; }
    float s2 = 0.f;
    for (int c = 0; c < 32; ++c) { wgt[c] = wgt[c] / s * vals[c]; s2 += wgt[c]; }
    float inv = 1.f / s2;
    for (int c = 0; c < 32; ++c) wgt[c] *= inv;
  }
  __syncthreads();
  if (t < 64) {
    float o = 0.f;
#pragma unroll
    for (int k = 0; k < 32; ++k) o += wgt[k] * xk[k * 65 + t];
    out[(size_t)b * 64 + t] = rs_b * o;
  }
}

// ---------------- launch ----------------
extern "C" void kernel_launch(void* const* d_in, const int* in_sizes, int n_in,
                              void* d_out, int out_size, void* d_ws, size_t ws_size,
                              hipStream_t stream) {
  const float* X   = (const float*)d_in[0];
  const float* ppr = (const float*)d_in[1];
  const float* W1  = (const float*)d_in[2];
  const float* W2  = (const float*)d_in[3];
  const float* W3  = (const float*)d_in[4];
  float* out = (float*)d_out;
  char* ws = (char*)d_ws;

  u16*  w1t = (u16*)(ws + 0);                    // 256x512 bf16
  u16*  w2t = (u16*)(ws + 262144);               // 256x256 bf16
  u16*  w3t = (u16*)(ws + 393216);               // 64x256 bf16
  float* lg = (float*)(ws + 458752);             // 65536x64 fp32 (16 MB)
  float* cv = (float*)(ws + 17235968);           // 8192x256 cand vals (8 MB)
  int*   ci = (int*)(ws + 25624576);             // 8192x256 cand idx (8 MB)
  int*   cq = (int*)(ws + 34013184);             // 8192 counts
  float* gs = (float*)(ws + 34045952);           // 8192 partial sums

  (void)in_sizes; (void)n_in; (void)out_size; (void)ws_size;

  conv_weights<<<832, 256, 0, stream>>>(W1, W2, W3, w1t, w2t, w3t);
  mega<<<10240, 256, 0, stream>>>(ppr, cv, ci, cq, gs, X, w1t, w2t, w3t, lg);
  merge_medoid<<<2048, 256, 0, stream>>>(ppr, cv, ci, cq, gs, lg, out);
}

// Round 12
// 181.183 us; speedup vs baseline: 1.5540x; 1.5540x over previous
//
#include <hip/hip_runtime.h>
#include <hip/hip_bf16.h>

typedef unsigned short u16;
typedef __attribute__((ext_vector_type(8))) __bf16 bf16x8;
typedef __attribute__((ext_vector_type(4))) float f32x4;

#define AS1 __attribute__((address_space(1)))
#define AS3 __attribute__((address_space(3)))

__device__ inline void gload_lds16(const void* g, void* l) {
  __builtin_amdgcn_global_load_lds((const AS1 void*)g, (AS3 void*)l, 16, 0, 0);
}

__device__ inline u16 f2bf(float f) {
  __bf16 h = (__bf16)f;
  return __builtin_bit_cast(u16, h);
}

// non-temporal streaming load: 512MB single-use stream should bypass L2/L3
__device__ inline f32x4 ldnt(const f32x4* p) {
  return __builtin_nontemporal_load(p);
}

// ---------------- fused weight transpose + bf16 convert ----------------
__global__ void conv_weights(const float* __restrict__ W1, const float* __restrict__ W2,
                             const float* __restrict__ W3, u16* __restrict__ w1t,
                             u16* __restrict__ w2t, u16* __restrict__ w3t) {
  int e = blockIdx.x * 256 + threadIdx.x;          // 0 .. 212991
  if (e < 131072) {
    int h = e >> 9, f = e & 511;
    w1t[e] = f2bf(W1[f * 256 + h]);
  } else if (e < 196608) {
    int x = e - 131072;
    int n = x >> 8, k = x & 255;
    w2t[x] = f2bf(W2[k * 256 + n]);
  } else if (e < 212992) {
    int x = e - 196608;
    int n = x >> 8, k = x & 255;
    w3t[x] = f2bf(W3[k * 64 + n]);
  }
}

// ================= fully-fused MLP (R8-identical) =================
__global__ __launch_bounds__(256, 2) void mlp_kernel(const float* __restrict__ X,
                                                     const u16* __restrict__ W1t,
                                                     const u16* __restrict__ W2t,
                                                     const u16* __restrict__ W3t,
                                                     float* __restrict__ lg) {
  __shared__ alignas(16) char smem[69632];
  u16* As   = (u16*)smem;                 // [64][32]   4 KB
  u16* Bs   = (u16*)(smem + 4096);        // [256][32] 16 KB
  u16* h1s  = (u16*)(smem + 20480);       // [64][256] 32 KB, elem-idx ^ ((row&7)<<3)
  u16* quad = (u16*)(smem + 53248);       // [64][64]   8 KB, swizzled
  u16* w3s  = (u16*)(smem + 61440);       // [64][64]   8 KB, swizzled
  const int bm = blockIdx.x, t = threadIdx.x;
  const int wid = t >> 6, lane = t & 63;
  const int wr = wid >> 1, wc = wid & 1;
  const int l15 = lane & 15, lk = lane >> 4;
  const f32x4 z = {0.f, 0.f, 0.f, 0.f};

  // ---- phase 1: h1s = relu(X[bm stripe] @ W1) ----
  {
    f32x4 acc[2][8];
#pragma unroll
    for (int i = 0; i < 2; ++i)
#pragma unroll
      for (int j = 0; j < 8; ++j) acc[i][j] = z;

    for (int k0 = 0; k0 < 512; k0 += 32) {
#pragma unroll
      for (int it = 0; it < 4; ++it) {
        int s = it * 256 + t;
        gload_lds16(W1t + (size_t)(s >> 2) * 512 + k0 + (s & 3) * 8,
                    &Bs[(it * 256 + wid * 64) * 8]);
      }
      {
        const float* src = X + (size_t)(bm * 64 + (t >> 2)) * 512 + k0 + (t & 3) * 8;
        float4 v0 = *(const float4*)src;
        float4 v1 = *(const float4*)(src + 4);
        bf16x8 wv;
        wv[0] = (__bf16)v0.x; wv[1] = (__bf16)v0.y; wv[2] = (__bf16)v0.z; wv[3] = (__bf16)v0.w;
        wv[4] = (__bf16)v1.x; wv[5] = (__bf16)v1.y; wv[6] = (__bf16)v1.z; wv[7] = (__bf16)v1.w;
        *(bf16x8*)&As[t * 8] = wv;
      }
      __syncthreads();
      bf16x8 af[2], bfr[8];
#pragma unroll
      for (int i = 0; i < 2; ++i)
        af[i] = *(const bf16x8*)&As[(wr * 32 + i * 16 + l15) * 32 + lk * 8];
#pragma unroll
      for (int j = 0; j < 8; ++j)
        bfr[j] = *(const bf16x8*)&Bs[(wc * 128 + j * 16 + l15) * 32 + lk * 8];
#pragma unroll
      for (int i = 0; i < 2; ++i)
#pragma unroll
        for (int j = 0; j < 8; ++j)
          acc[i][j] = __builtin_amdgcn_mfma_f32_16x16x32_bf16(af[i], bfr[j], acc[i][j], 0, 0, 0);
      __syncthreads();
    }
#pragma unroll
    for (int i = 0; i < 2; ++i)
#pragma unroll
      for (int j = 0; j < 8; ++j)
#pragma unroll
        for (int r = 0; r < 4; ++r) {
          int row = wr * 32 + i * 16 + lk * 4 + r;
          int col = wc * 128 + j * 16 + l15;
          h1s[(row * 256 + col) ^ ((row & 7) << 3)] = f2bf(fmaxf(acc[i][j][r], 0.f));
        }
    __syncthreads();
  }

  // ---- phase 2: acc2 = h1s @ W2 ----
  f32x4 acc2[2][8];
#pragma unroll
  for (int i = 0; i < 2; ++i)
#pragma unroll
    for (int j = 0; j < 8; ++j) acc2[i][j] = z;

  for (int k0 = 0; k0 < 256; k0 += 32) {
#pragma unroll
    for (int it = 0; it < 4; ++it) {
      int s = it * 256 + t;
      gload_lds16(W2t + (size_t)(s >> 2) * 256 + k0 + (s & 3) * 8,
                  &Bs[(it * 256 + wid * 64) * 8]);
    }
    __syncthreads();
    bf16x8 af[2], bfr[8];
#pragma unroll
    for (int i = 0; i < 2; ++i) {
      int row = wr * 32 + i * 16 + l15;
      af[i] = *(const bf16x8*)&h1s[(row * 256 + k0 + lk * 8) ^ ((row & 7) << 3)];
    }
#pragma unroll
    for (int j = 0; j < 8; ++j)
      bfr[j] = *(const bf16x8*)&Bs[(wc * 128 + j * 16 + l15) * 32 + lk * 8];
#pragma unroll
    for (int i = 0; i < 2; ++i)
#pragma unroll
      for (int j = 0; j < 8; ++j)
        acc2[i][j] = __builtin_amdgcn_mfma_f32_16x16x32_bf16(af[i], bfr[j], acc2[i][j], 0, 0, 0);
    __syncthreads();
  }

  // ---- phase 3: lg = relu(acc2) @ W3 via swizzled LDS bounce ----
  f32x4 acc3[4];
#pragma unroll
  for (int j = 0; j < 4; ++j) acc3[j] = z;

#pragma unroll
  for (int kk = 0; kk < 4; ++kk) {
    if (wc == (kk >> 1)) {
#pragma unroll
      for (int i = 0; i < 2; ++i)
#pragma unroll
        for (int j4 = 0; j4 < 4; ++j4) {
          int j = (kk & 1) * 4 + j4;
#pragma unroll
          for (int r = 0; r < 4; ++r) {
            int row = wr * 32 + i * 16 + lk * 4 + r;
            int c   = j4 * 16 + l15;
            quad[(row * 64 + c) ^ ((row & 7) << 3)] = f2bf(fmaxf(acc2[i][j][r], 0.f));
          }
        }
    }
#pragma unroll
    for (int it = 0; it < 2; ++it) {
      int s = it * 256 + t;
      int col = s >> 3;
      int koff = ((s ^ (col & 7)) & 7) * 8;
      gload_lds16(W3t + (size_t)col * 256 + kk * 64 + koff, &w3s[(it * 256 + wid * 64) * 8]);
    }
    __syncthreads();
    bf16x8 af2, bfr2[4];
#pragma unroll
    for (int ks = 0; ks < 2; ++ks) {
#pragma unroll
      for (int j2 = 0; j2 < 4; ++j2) {
        int col = j2 * 16 + l15;
        bfr2[j2] = *(const bf16x8*)&w3s[(col * 64 + ks * 32 + lk * 8) ^ ((col & 7) << 3)];
      }
      {
        int row = wid * 16 + l15;
        af2 = *(const bf16x8*)&quad[(row * 64 + ks * 32 + lk * 8) ^ ((row & 7) << 3)];
      }
#pragma unroll
      for (int j2 = 0; j2 < 4; ++j2)
        acc3[j2] = __builtin_amdgcn_mfma_f32_16x16x32_bf16(af2, bfr2[j2], acc3[j2], 0, 0, 0);
    }
    __syncthreads();
  }

#pragma unroll
  for (int j2 = 0; j2 < 4; ++j2) {
    int col = j2 * 16 + l15;
#pragma unroll
    for (int r = 0; r < 4; ++r) {
      int row = wid * 16 + lk * 4 + r;
      lg[(size_t)(bm * 64 + row) * 64 + col] = acc3[j2][r];
    }
  }
}

// ================= fused topk + soft-k-medoid per ppr row =================
// R8 structure with three scan/extraction changes:
//  1. NO min-waves launch_bounds -> VGPR free (~110), 16 waves/CU. R8's
//     (256,4) capped VGPR at 64 and starved the load pipeline (R9 evidence).
//  2. Scan = 4 macro-batches x 16 upfront NON-TEMPORAL float4 loads
//     (single-use 512MB stream; nt bypasses L2/L3 pollution). unroll-1 macro
//     loop keeps staging at 64 VGPR.
//  3. Extraction = wave-parallel rank-select: rank(p) = #{q: (vq,iq) strictly
//     better}; rank<32 wins. O(n^2/256), ONE barrier, no serial tail.
//     Order-independent of atomic insertion order -> deterministic; matches
//     jax.lax.top_k (val desc, idx asc).
__global__ __launch_bounds__(256) void topk_medoid(const float* __restrict__ ppr,
                                                   const float* __restrict__ lg,
                                                   float* __restrict__ out) {
  __shared__ alignas(16) char smem[13312];
  float* cvals   = (float*)smem;              // [1024] (phase 1-2)
  int*   cidx    = (int*)(smem + 4096);       // [1024] (phase 1-2)
  float* xk      = (float*)smem;              // [32][65] (phase 3, aliases cands)
  float* l2m     = (float*)(smem + 8448);     // [32][33]
  float* vals    = (float*)(smem + 12672);    // [32]
  int*   idxs    = (int*)(smem + 12800);      // [32] (also fallback's sel)
  float* dist    = (float*)(smem + 12928);    // [32]
  float* wgt     = (float*)(smem + 13056);    // [32]
  float* partial = (float*)(smem + 13184);    // [4]
  int*   cnt     = (int*)(smem + 13200);      // [1]
  float* rsum    = (float*)(smem + 13204);    // [1]

  const int b = blockIdx.x, t = threadIdx.x;
  const int lane = t & 63, wid = t >> 6;
  const float* row = ppr + (size_t)b * 65536;
  const f32x4* rp = (const f32x4*)row;        // 16384 f32x4
  const float T0 = 0.997f;

  if (t == 0) *cnt = 0;
  __syncthreads();

  // ---- phase 1: scan (4 macro-batches of 16 nt-loads upfront) ----
  float sum = 0.f;
#pragma unroll 1
  for (int mb = 0; mb < 4; ++mb) {
    f32x4 v[16];
#pragma unroll
    for (int i = 0; i < 16; ++i) v[i] = ldnt(rp + (mb * 16 + i) * 256 + t);
#pragma unroll
    for (int i = 0; i < 16; ++i) {
      f32x4 x = v[i];
      sum += (x[0] + x[1]) + (x[2] + x[3]);
      float mx = fmaxf(fmaxf(x[0], x[1]), fmaxf(x[2], x[3]));
      if (mx > T0) {
        int fb = ((mb * 16 + i) * 256 + t) * 4;
#pragma unroll
        for (int j = 0; j < 4; ++j) {
          if (x[j] > T0) {
            int p = atomicAdd(cnt, 1);
            if (p < 1024) { cvals[p] = x[j]; cidx[p] = fb + j; }
          }
        }
      }
    }
  }
#pragma unroll
  for (int off = 32; off > 0; off >>= 1) sum += __shfl_down(sum, off);
  if (lane == 0) partial[wid] = sum;
  __syncthreads();

  // ---- phase 2: extraction ----
  const int ncand = *cnt;
  const int n = ncand < 1024 ? ncand : 1024;
  if (t == 0) *rsum = (partial[0] + partial[1]) + (partial[2] + partial[3]);

  if (n >= 32 && ncand <= 1024) {
    // parallel rank-select: all 256 threads, one barrier below
    for (int p = t; p < n; p += 256) {
      float v = cvals[p];
      int id = cidx[p];
      int rank = 0;
      for (int q = 0; q < n; ++q) {
        float vq = cvals[q];            // broadcast reads (same addr all lanes)
        int   iq = cidx[q];
        rank += (vq > v || (vq == v && iq < id)) ? 1 : 0;
      }
      if (rank < 32) { vals[rank] = v; idxs[rank] = id; }
    }
  } else if (wid == 0) {
    // exact fallback (never taken for uniform data): wave0 serial argmax
    for (int r = 0; r < 32; ++r) {
      float bv = -__builtin_inff();
      int bi = 0x7fffffff;
      for (int p = lane; p < 65536; p += 64) {
        float xv = row[p];
        bool skip = false;
        for (int q = 0; q < r; ++q) skip = skip || (idxs[q] == p);
        if (!skip && (xv > bv || (xv == bv && p < bi))) { bv = xv; bi = p; }
      }
#pragma unroll
      for (int off = 32; off > 0; off >>= 1) {
        float ov = __shfl_down(bv, off);
        int   oi = __shfl_down(bi, off);
        if (ov > bv || (ov == bv && oi < bi)) { bv = ov; bi = oi; }
      }
      if (lane == 0) { vals[r] = bv; idxs[r] = bi; }
    }
  }
  __syncthreads();

  // ---- phase 3: medoid on own result ----
  const float rs_b = *rsum;
#pragma unroll
  for (int j = 0; j < 8; ++j) {
    int s = j * 256 + t;
    int r = s >> 6, c = s & 63;
    xk[r * 65 + c] = lg[(size_t)idxs[r] * 64 + c];
  }
  __syncthreads();
#pragma unroll
  for (int j = 0; j < 4; ++j) {
    int p = j * 256 + t;
    int c = p >> 5, m = p & 31;
    float d = 0.f;
#pragma unroll
    for (int ch = 0; ch < 64; ++ch) {
      float df = xk[c * 65 + ch] - xk[m * 65 + ch];
      d += df * df;
    }
    l2m[c * 33 + m] = sqrtf(d + 1e-12f);
  }
  __syncthreads();
  if (t < 32) {
    float d = 0.f;
#pragma unroll
    for (int m = 0; m < 32; ++m) d += vals[m] * l2m[t * 33 + m];
    if (vals[t] == 0.f) d = 3.402823466e+38f;
    dist[t] = d;
  }
  __syncthreads();
  if (t == 0) {
    float mx = -3.402823466e+38f;
    for (int c = 0; c < 32; ++c) mx = fmaxf(mx, -dist[c]);
    float s = 0.f;
    for (int c = 0; c < 32; ++c) { float e = expf(-dist[c] - mx); wgt[c] = e; s += e; }
    float s2 = 0.f;
    for (int c = 0; c < 32; ++c) { wgt[c] = wgt[c] / s * vals[c]; s2 += wgt[c]; }
    float inv = 1.f / s2;
    for (int c = 0; c < 32; ++c) wgt[c] *= inv;
  }
  __syncthreads();
  if (t < 64) {
    float o = 0.f;
#pragma unroll
    for (int k = 0; k < 32; ++k) o += wgt[k] * xk[k * 65 + t];
    out[(size_t)b * 64 + t] = rs_b * o;
  }
}

// ---------------- launch ----------------
extern "C" void kernel_launch(void* const* d_in, const int* in_sizes, int n_in,
                              void* d_out, int out_size, void* d_ws, size_t ws_size,
                              hipStream_t stream) {
  const float* X   = (const float*)d_in[0];
  const float* ppr = (const float*)d_in[1];
  const float* W1  = (const float*)d_in[2];
  const float* W2  = (const float*)d_in[3];
  const float* W3  = (const float*)d_in[4];
  float* out = (float*)d_out;
  char* ws = (char*)d_ws;

  u16*  w1t = (u16*)(ws + 0);                    // 256x512 bf16
  u16*  w2t = (u16*)(ws + 262144);               // 256x256 bf16
  u16*  w3t = (u16*)(ws + 393216);               // 64x256 bf16
  float* lg = (float*)(ws + 458752);             // 65536x64 fp32

  (void)in_sizes; (void)n_in; (void)out_size; (void)ws_size;

  conv_weights<<<832, 256, 0, stream>>>(W1, W2, W3, w1t, w2t, w3t);
  mlp_kernel<<<1024, 256, 0, stream>>>(X, w1t, w2t, w3t, lg);
  topk_medoid<<<2048, 256, 0, stream>>>(ppr, lg, out);
}

// Round 13
// 173.770 us; speedup vs baseline: 1.6203x; 1.0427x over previous
//
#include <hip/hip_runtime.h>
#include <hip/hip_bf16.h>

typedef unsigned short u16;
typedef __attribute__((ext_vector_type(8))) __bf16 bf16x8;
typedef __attribute__((ext_vector_type(4))) float f32x4;

#define AS1 __attribute__((address_space(1)))
#define AS3 __attribute__((address_space(3)))

__device__ inline void gload_lds16(const void* g, void* l) {
  __builtin_amdgcn_global_load_lds((const AS1 void*)g, (AS3 void*)l, 16, 0, 0);
}

__device__ inline u16 f2bf(float f) {
  __bf16 h = (__bf16)f;
  return __builtin_bit_cast(u16, h);
}

// non-temporal streaming load: 512MB single-use stream bypasses L2/L3
__device__ inline f32x4 ldnt(const f32x4* p) {
  return __builtin_nontemporal_load(p);
}

// ---------------- fused weight transpose + bf16 convert ----------------
__global__ void conv_weights(const float* __restrict__ W1, const float* __restrict__ W2,
                             const float* __restrict__ W3, u16* __restrict__ w1t,
                             u16* __restrict__ w2t, u16* __restrict__ w3t) {
  int e = blockIdx.x * 256 + threadIdx.x;          // 0 .. 212991
  if (e < 131072) {
    int h = e >> 9, f = e & 511;
    w1t[e] = f2bf(W1[f * 256 + h]);
  } else if (e < 196608) {
    int x = e - 131072;
    int n = x >> 8, k = x & 255;
    w2t[x] = f2bf(W2[k * 256 + n]);
  } else if (e < 212992) {
    int x = e - 196608;
    int n = x >> 8, k = x & 255;
    w3t[x] = f2bf(W3[k * 64 + n]);
  }
}

// ================= fully-fused MLP, BK=64 =================
// R12 structure with BK 32->64 in phases 1+2: barrier-drain count halved
// (48 -> 24 per block), staged bytes identical, LDS 72KB -> still 2 blk/CU.
// As/Bs use the proven w3s XOR-chunk swizzle: 16B-chunk ^= (row&7) — Bs via
// pre-swizzled gload SOURCE (rule 21: gload dst must stay linear), As via
// swizzled ds_write (we control both sides).
__global__ __launch_bounds__(256, 2) void mlp_kernel(const float* __restrict__ X,
                                                     const u16* __restrict__ W1t,
                                                     const u16* __restrict__ W2t,
                                                     const u16* __restrict__ W3t,
                                                     float* __restrict__ lg) {
  __shared__ alignas(16) char smem[73728];
  u16* As   = (u16*)smem;                 // [64][64]   8 KB swz (phase 1)
  u16* Bs   = (u16*)(smem + 8192);        // [256][64] 32 KB swz (phase 1,2)
  u16* h1s  = (u16*)(smem + 40960);       // [64][256] 32 KB swz (phase 1->2)
  u16* quad = (u16*)smem;                 // [64][64]   8 KB swz (phase 3, reuses As)
  u16* w3s  = (u16*)(smem + 8192);        // [64][64]   8 KB swz (phase 3, reuses Bs)
  const int bm = blockIdx.x, t = threadIdx.x;
  const int wid = t >> 6, lane = t & 63;
  const int wr = wid >> 1, wc = wid & 1;
  const int l15 = lane & 15, lk = lane >> 4;
  const f32x4 z = {0.f, 0.f, 0.f, 0.f};

  // ---- phase 1: h1s = relu(X[bm stripe] @ W1), K=512, BK=64 ----
  {
    f32x4 acc[2][8];
#pragma unroll
    for (int i = 0; i < 2; ++i)
#pragma unroll
      for (int j = 0; j < 8; ++j) acc[i][j] = z;

    for (int k0 = 0; k0 < 512; k0 += 64) {
#pragma unroll
      for (int it = 0; it < 8; ++it) {          // W1 tile [256][64], src pre-swz
        int s = it * 256 + t;
        int n = s >> 3;
        int koff = ((s ^ (n & 7)) & 7) * 8;
        gload_lds16(W1t + (size_t)n * 512 + k0 + koff, &Bs[s * 8]);
      }
#pragma unroll
      for (int it = 0; it < 2; ++it) {          // X tile [64][64] fp32->bf16, swz write
        int s = it * 256 + t;
        int row = s >> 3, c = s & 7;
        const float* src = X + (size_t)(bm * 64 + row) * 512 + k0 + c * 8;
        float4 v0 = *(const float4*)src;
        float4 v1 = *(const float4*)(src + 4);
        bf16x8 wv;
        wv[0] = (__bf16)v0.x; wv[1] = (__bf16)v0.y; wv[2] = (__bf16)v0.z; wv[3] = (__bf16)v0.w;
        wv[4] = (__bf16)v1.x; wv[5] = (__bf16)v1.y; wv[6] = (__bf16)v1.z; wv[7] = (__bf16)v1.w;
        *(bf16x8*)&As[(row * 64 + c * 8) ^ ((row & 7) << 3)] = wv;
      }
      __syncthreads();
#pragma unroll
      for (int ks = 0; ks < 2; ++ks) {
        bf16x8 af[2], bfr[8];
#pragma unroll
        for (int i = 0; i < 2; ++i) {
          int row = wr * 32 + i * 16 + l15;
          af[i] = *(const bf16x8*)&As[(row * 64 + ks * 32 + lk * 8) ^ ((row & 7) << 3)];
        }
#pragma unroll
        for (int j = 0; j < 8; ++j) {
          int n = wc * 128 + j * 16 + l15;
          bfr[j] = *(const bf16x8*)&Bs[(n * 64 + ks * 32 + lk * 8) ^ ((n & 7) << 3)];
        }
#pragma unroll
        for (int i = 0; i < 2; ++i)
#pragma unroll
          for (int j = 0; j < 8; ++j)
            acc[i][j] = __builtin_amdgcn_mfma_f32_16x16x32_bf16(af[i], bfr[j], acc[i][j], 0, 0, 0);
      }
      __syncthreads();
    }
#pragma unroll
    for (int i = 0; i < 2; ++i)
#pragma unroll
      for (int j = 0; j < 8; ++j)
#pragma unroll
        for (int r = 0; r < 4; ++r) {
          int row = wr * 32 + i * 16 + lk * 4 + r;
          int col = wc * 128 + j * 16 + l15;
          h1s[(row * 256 + col) ^ ((row & 7) << 3)] = f2bf(fmaxf(acc[i][j][r], 0.f));
        }
    __syncthreads();
  }

  // ---- phase 2: acc2 = h1s @ W2, K=256, BK=64 ----
  f32x4 acc2[2][8];
#pragma unroll
  for (int i = 0; i < 2; ++i)
#pragma unroll
    for (int j = 0; j < 8; ++j) acc2[i][j] = z;

  for (int k0 = 0; k0 < 256; k0 += 64) {
#pragma unroll
    for (int it = 0; it < 8; ++it) {            // W2 tile [256][64], src pre-swz
      int s = it * 256 + t;
      int n = s >> 3;
      int koff = ((s ^ (n & 7)) & 7) * 8;
      gload_lds16(W2t + (size_t)n * 256 + k0 + koff, &Bs[s * 8]);
    }
    __syncthreads();
#pragma unroll
    for (int ks = 0; ks < 2; ++ks) {
      bf16x8 af[2], bfr[8];
#pragma unroll
      for (int i = 0; i < 2; ++i) {
        int row = wr * 32 + i * 16 + l15;
        af[i] = *(const bf16x8*)&h1s[(row * 256 + k0 + ks * 32 + lk * 8) ^ ((row & 7) << 3)];
      }
#pragma unroll
      for (int j = 0; j < 8; ++j) {
        int n = wc * 128 + j * 16 + l15;
        bfr[j] = *(const bf16x8*)&Bs[(n * 64 + ks * 32 + lk * 8) ^ ((n & 7) << 3)];
      }
#pragma unroll
      for (int i = 0; i < 2; ++i)
#pragma unroll
        for (int j = 0; j < 8; ++j)
          acc2[i][j] = __builtin_amdgcn_mfma_f32_16x16x32_bf16(af[i], bfr[j], acc2[i][j], 0, 0, 0);
    }
    __syncthreads();
  }

  // ---- phase 3: lg = relu(acc2) @ W3 via swizzled LDS bounce (R8-verified) ----
  f32x4 acc3[4];
#pragma unroll
  for (int j = 0; j < 4; ++j) acc3[j] = z;

#pragma unroll
  for (int kk = 0; kk < 4; ++kk) {
    if (wc == (kk >> 1)) {
#pragma unroll
      for (int i = 0; i < 2; ++i)
#pragma unroll
        for (int j4 = 0; j4 < 4; ++j4) {
          int j = (kk & 1) * 4 + j4;
#pragma unroll
          for (int r = 0; r < 4; ++r) {
            int row = wr * 32 + i * 16 + lk * 4 + r;
            int c   = j4 * 16 + l15;
            quad[(row * 64 + c) ^ ((row & 7) << 3)] = f2bf(fmaxf(acc2[i][j][r], 0.f));
          }
        }
    }
#pragma unroll
    for (int it = 0; it < 2; ++it) {
      int s = it * 256 + t;
      int col = s >> 3;
      int koff = ((s ^ (col & 7)) & 7) * 8;
      gload_lds16(W3t + (size_t)col * 256 + kk * 64 + koff, &w3s[(it * 256 + wid * 64) * 8]);
    }
    __syncthreads();
    bf16x8 af2, bfr2[4];
#pragma unroll
    for (int ks = 0; ks < 2; ++ks) {
#pragma unroll
      for (int j2 = 0; j2 < 4; ++j2) {
        int col = j2 * 16 + l15;
        bfr2[j2] = *(const bf16x8*)&w3s[(col * 64 + ks * 32 + lk * 8) ^ ((col & 7) << 3)];
      }
      {
        int row = wid * 16 + l15;
        af2 = *(const bf16x8*)&quad[(row * 64 + ks * 32 + lk * 8) ^ ((row & 7) << 3)];
      }
#pragma unroll
      for (int j2 = 0; j2 < 4; ++j2)
        acc3[j2] = __builtin_amdgcn_mfma_f32_16x16x32_bf16(af2, bfr2[j2], acc3[j2], 0, 0, 0);
    }
    __syncthreads();
  }

#pragma unroll
  for (int j2 = 0; j2 < 4; ++j2) {
    int col = j2 * 16 + l15;
#pragma unroll
    for (int r = 0; r < 4; ++r) {
      int row = wid * 16 + lk * 4 + r;
      lg[(size_t)(bm * 64 + row) * 64 + col] = acc3[j2][r];
    }
  }
}

// ================= fused topk + soft-k-medoid per ppr row (R12-verified) =================
__global__ __launch_bounds__(256) void topk_medoid(const float* __restrict__ ppr,
                                                   const float* __restrict__ lg,
                                                   float* __restrict__ out) {
  __shared__ alignas(16) char smem[13312];
  float* cvals   = (float*)smem;              // [1024] (phase 1-2)
  int*   cidx    = (int*)(smem + 4096);       // [1024] (phase 1-2)
  float* xk      = (float*)smem;              // [32][65] (phase 3, aliases cands)
  float* l2m     = (float*)(smem + 8448);     // [32][33]
  float* vals    = (float*)(smem + 12672);    // [32]
  int*   idxs    = (int*)(smem + 12800);      // [32] (also fallback's sel)
  float* dist    = (float*)(smem + 12928);    // [32]
  float* wgt     = (float*)(smem + 13056);    // [32]
  float* partial = (float*)(smem + 13184);    // [4]
  int*   cnt     = (int*)(smem + 13200);      // [1]
  float* rsum    = (float*)(smem + 13204);    // [1]

  const int b = blockIdx.x, t = threadIdx.x;
  const int lane = t & 63, wid = t >> 6;
  const float* row = ppr + (size_t)b * 65536;
  const f32x4* rp = (const f32x4*)row;        // 16384 f32x4
  const float T0 = 0.997f;

  if (t == 0) *cnt = 0;
  __syncthreads();

  // ---- phase 1: scan (4 macro-batches of 16 nt-loads upfront) ----
  float sum = 0.f;
#pragma unroll 1
  for (int mb = 0; mb < 4; ++mb) {
    f32x4 v[16];
#pragma unroll
    for (int i = 0; i < 16; ++i) v[i] = ldnt(rp + (mb * 16 + i) * 256 + t);
#pragma unroll
    for (int i = 0; i < 16; ++i) {
      f32x4 x = v[i];
      sum += (x[0] + x[1]) + (x[2] + x[3]);
      float mx = fmaxf(fmaxf(x[0], x[1]), fmaxf(x[2], x[3]));
      if (mx > T0) {
        int fb = ((mb * 16 + i) * 256 + t) * 4;
#pragma unroll
        for (int j = 0; j < 4; ++j) {
          if (x[j] > T0) {
            int p = atomicAdd(cnt, 1);
            if (p < 1024) { cvals[p] = x[j]; cidx[p] = fb + j; }
          }
        }
      }
    }
  }
#pragma unroll
  for (int off = 32; off > 0; off >>= 1) sum += __shfl_down(sum, off);
  if (lane == 0) partial[wid] = sum;
  __syncthreads();

  // ---- phase 2: extraction ----
  const int ncand = *cnt;
  const int n = ncand < 1024 ? ncand : 1024;
  if (t == 0) *rsum = (partial[0] + partial[1]) + (partial[2] + partial[3]);

  if (n >= 32 && ncand <= 1024) {
    // parallel rank-select: rank(p) = #{q strictly better}; rank<32 wins.
    for (int p = t; p < n; p += 256) {
      float v = cvals[p];
      int id = cidx[p];
      int rank = 0;
      for (int q = 0; q < n; ++q) {
        float vq = cvals[q];
        int   iq = cidx[q];
        rank += (vq > v || (vq == v && iq < id)) ? 1 : 0;
      }
      if (rank < 32) { vals[rank] = v; idxs[rank] = id; }
    }
  } else if (wid == 0) {
    // exact fallback (never taken for uniform data)
    for (int r = 0; r < 32; ++r) {
      float bv = -__builtin_inff();
      int bi = 0x7fffffff;
      for (int p = lane; p < 65536; p += 64) {
        float xv = row[p];
        bool skip = false;
        for (int q = 0; q < r; ++q) skip = skip || (idxs[q] == p);
        if (!skip && (xv > bv || (xv == bv && p < bi))) { bv = xv; bi = p; }
      }
#pragma unroll
      for (int off = 32; off > 0; off >>= 1) {
        float ov = __shfl_down(bv, off);
        int   oi = __shfl_down(bi, off);
        if (ov > bv || (ov == bv && oi < bi)) { bv = ov; bi = oi; }
      }
      if (lane == 0) { vals[r] = bv; idxs[r] = bi; }
    }
  }
  __syncthreads();

  // ---- phase 3: medoid on own result ----
  const float rs_b = *rsum;
#pragma unroll
  for (int j = 0; j < 8; ++j) {
    int s = j * 256 + t;
    int r = s >> 6, c = s & 63;
    xk[r * 65 + c] = lg[(size_t)idxs[r] * 64 + c];
  }
  __syncthreads();
#pragma unroll
  for (int j = 0; j < 4; ++j) {
    int p = j * 256 + t;
    int c = p >> 5, m = p & 31;
    float d = 0.f;
#pragma unroll
    for (int ch = 0; ch < 64; ++ch) {
      float df = xk[c * 65 + ch] - xk[m * 65 + ch];
      d += df * df;
    }
    l2m[c * 33 + m] = sqrtf(d + 1e-12f);
  }
  __syncthreads();
  if (t < 32) {
    float d = 0.f;
#pragma unroll
    for (int m = 0; m < 32; ++m) d += vals[m] * l2m[t * 33 + m];
    if (vals[t] == 0.f) d = 3.402823466e+38f;
    dist[t] = d;
  }
  __syncthreads();
  if (t == 0) {
    float mx = -3.402823466e+38f;
    for (int c = 0; c < 32; ++c) mx = fmaxf(mx, -dist[c]);
    float s = 0.f;
    for (int c = 0; c < 32; ++c) { float e = expf(-dist[c] - mx); wgt[c] = e; s += e; }
    float s2 = 0.f;
    for (int c = 0; c < 32; ++c) { wgt[c] = wgt[c] / s * vals[c]; s2 += wgt[c]; }
    float inv = 1.f / s2;
    for (int c = 0; c < 32; ++c) wgt[c] *= inv;
  }
  __syncthreads();
  if (t < 64) {
    float o = 0.f;
#pragma unroll
    for (int k = 0; k < 32; ++k) o += wgt[k] * xk[k * 65 + t];
    out[(size_t)b * 64 + t] = rs_b * o;
  }
}

// ---------------- launch ----------------
extern "C" void kernel_launch(void* const* d_in, const int* in_sizes, int n_in,
                              void* d_out, int out_size, void* d_ws, size_t ws_size,
                              hipStream_t stream) {
  const float* X   = (const float*)d_in[0];
  const float* ppr = (const float*)d_in[1];
  const float* W1  = (const float*)d_in[2];
  const float* W2  = (const float*)d_in[3];
  const float* W3  = (const float*)d_in[4];
  float* out = (float*)d_out;
  char* ws = (char*)d_ws;

  u16*  w1t = (u16*)(ws + 0);                    // 256x512 bf16
  u16*  w2t = (u16*)(ws + 262144);               // 256x256 bf16
  u16*  w3t = (u16*)(ws + 393216);               // 64x256 bf16
  float* lg = (float*)(ws + 458752);             // 65536x64 fp32

  (void)in_sizes; (void)n_in; (void)out_size; (void)ws_size;

  conv_weights<<<832, 256, 0, stream>>>(W1, W2, W3, w1t, w2t, w3t);
  mlp_kernel<<<1024, 256, 0, stream>>>(X, w1t, w2t, w3t, lg);
  topk_medoid<<<2048, 256, 0, stream>>>(ppr, lg, out);
}

// Round 14
// 172.802 us; speedup vs baseline: 1.6293x; 1.0056x over previous
//
#include <hip/hip_runtime.h>
#include <hip/hip_bf16.h>

typedef unsigned short u16;
typedef __attribute__((ext_vector_type(8))) __bf16 bf16x8;
typedef __attribute__((ext_vector_type(4))) float f32x4;

#define AS1 __attribute__((address_space(1)))
#define AS3 __attribute__((address_space(3)))

__device__ inline void gload_lds16(const void* g, void* l) {
  __builtin_amdgcn_global_load_lds((const AS1 void*)g, (AS3 void*)l, 16, 0, 0);
}

__device__ inline u16 f2bf(float f) {
  __bf16 h = (__bf16)f;
  return __builtin_bit_cast(u16, h);
}

// non-temporal streaming load: 512MB single-use stream bypasses L2/L3
__device__ inline f32x4 ldnt(const f32x4* p) {
  return __builtin_nontemporal_load(p);
}

// ---------------- fused weight transpose + bf16 convert ----------------
__global__ void conv_weights(const float* __restrict__ W1, const float* __restrict__ W2,
                             const float* __restrict__ W3, u16* __restrict__ w1t,
                             u16* __restrict__ w2t, u16* __restrict__ w3t) {
  int e = blockIdx.x * 256 + threadIdx.x;          // 0 .. 212991
  if (e < 131072) {
    int h = e >> 9, f = e & 511;
    w1t[e] = f2bf(W1[f * 256 + h]);
  } else if (e < 196608) {
    int x = e - 131072;
    int n = x >> 8, k = x & 255;
    w2t[x] = f2bf(W2[k * 256 + n]);
  } else if (e < 212992) {
    int x = e - 196608;
    int n = x >> 8, k = x & 255;
    w3t[x] = f2bf(W3[k * 64 + n]);
  }
}

// ================= fully-fused MLP, BK=64 (R13-verified, frozen) =================
__global__ __launch_bounds__(256, 2) void mlp_kernel(const float* __restrict__ X,
                                                     const u16* __restrict__ W1t,
                                                     const u16* __restrict__ W2t,
                                                     const u16* __restrict__ W3t,
                                                     float* __restrict__ lg) {
  __shared__ alignas(16) char smem[73728];
  u16* As   = (u16*)smem;                 // [64][64]   8 KB swz (phase 1)
  u16* Bs   = (u16*)(smem + 8192);        // [256][64] 32 KB swz (phase 1,2)
  u16* h1s  = (u16*)(smem + 40960);       // [64][256] 32 KB swz (phase 1->2)
  u16* quad = (u16*)smem;                 // [64][64]   8 KB swz (phase 3, reuses As)
  u16* w3s  = (u16*)(smem + 8192);        // [64][64]   8 KB swz (phase 3, reuses Bs)
  const int bm = blockIdx.x, t = threadIdx.x;
  const int wid = t >> 6, lane = t & 63;
  const int wr = wid >> 1, wc = wid & 1;
  const int l15 = lane & 15, lk = lane >> 4;
  const f32x4 z = {0.f, 0.f, 0.f, 0.f};

  // ---- phase 1: h1s = relu(X[bm stripe] @ W1), K=512, BK=64 ----
  {
    f32x4 acc[2][8];
#pragma unroll
    for (int i = 0; i < 2; ++i)
#pragma unroll
      for (int j = 0; j < 8; ++j) acc[i][j] = z;

    for (int k0 = 0; k0 < 512; k0 += 64) {
#pragma unroll
      for (int it = 0; it < 8; ++it) {          // W1 tile [256][64], src pre-swz
        int s = it * 256 + t;
        int n = s >> 3;
        int koff = ((s ^ (n & 7)) & 7) * 8;
        gload_lds16(W1t + (size_t)n * 512 + k0 + koff, &Bs[s * 8]);
      }
#pragma unroll
      for (int it = 0; it < 2; ++it) {          // X tile [64][64] fp32->bf16, swz write
        int s = it * 256 + t;
        int row = s >> 3, c = s & 7;
        const float* src = X + (size_t)(bm * 64 + row) * 512 + k0 + c * 8;
        float4 v0 = *(const float4*)src;
        float4 v1 = *(const float4*)(src + 4);
        bf16x8 wv;
        wv[0] = (__bf16)v0.x; wv[1] = (__bf16)v0.y; wv[2] = (__bf16)v0.z; wv[3] = (__bf16)v0.w;
        wv[4] = (__bf16)v1.x; wv[5] = (__bf16)v1.y; wv[6] = (__bf16)v1.z; wv[7] = (__bf16)v1.w;
        *(bf16x8*)&As[(row * 64 + c * 8) ^ ((row & 7) << 3)] = wv;
      }
      __syncthreads();
#pragma unroll
      for (int ks = 0; ks < 2; ++ks) {
        bf16x8 af[2], bfr[8];
#pragma unroll
        for (int i = 0; i < 2; ++i) {
          int row = wr * 32 + i * 16 + l15;
          af[i] = *(const bf16x8*)&As[(row * 64 + ks * 32 + lk * 8) ^ ((row & 7) << 3)];
        }
#pragma unroll
        for (int j = 0; j < 8; ++j) {
          int n = wc * 128 + j * 16 + l15;
          bfr[j] = *(const bf16x8*)&Bs[(n * 64 + ks * 32 + lk * 8) ^ ((n & 7) << 3)];
        }
#pragma unroll
        for (int i = 0; i < 2; ++i)
#pragma unroll
          for (int j = 0; j < 8; ++j)
            acc[i][j] = __builtin_amdgcn_mfma_f32_16x16x32_bf16(af[i], bfr[j], acc[i][j], 0, 0, 0);
      }
      __syncthreads();
    }
#pragma unroll
    for (int i = 0; i < 2; ++i)
#pragma unroll
      for (int j = 0; j < 8; ++j)
#pragma unroll
        for (int r = 0; r < 4; ++r) {
          int row = wr * 32 + i * 16 + lk * 4 + r;
          int col = wc * 128 + j * 16 + l15;
          h1s[(row * 256 + col) ^ ((row & 7) << 3)] = f2bf(fmaxf(acc[i][j][r], 0.f));
        }
    __syncthreads();
  }

  // ---- phase 2: acc2 = h1s @ W2, K=256, BK=64 ----
  f32x4 acc2[2][8];
#pragma unroll
  for (int i = 0; i < 2; ++i)
#pragma unroll
    for (int j = 0; j < 8; ++j) acc2[i][j] = z;

  for (int k0 = 0; k0 < 256; k0 += 64) {
#pragma unroll
    for (int it = 0; it < 8; ++it) {            // W2 tile [256][64], src pre-swz
      int s = it * 256 + t;
      int n = s >> 3;
      int koff = ((s ^ (n & 7)) & 7) * 8;
      gload_lds16(W2t + (size_t)n * 256 + k0 + koff, &Bs[s * 8]);
    }
    __syncthreads();
#pragma unroll
    for (int ks = 0; ks < 2; ++ks) {
      bf16x8 af[2], bfr[8];
#pragma unroll
      for (int i = 0; i < 2; ++i) {
        int row = wr * 32 + i * 16 + l15;
        af[i] = *(const bf16x8*)&h1s[(row * 256 + k0 + ks * 32 + lk * 8) ^ ((row & 7) << 3)];
      }
#pragma unroll
      for (int j = 0; j < 8; ++j) {
        int n = wc * 128 + j * 16 + l15;
        bfr[j] = *(const bf16x8*)&Bs[(n * 64 + ks * 32 + lk * 8) ^ ((n & 7) << 3)];
      }
#pragma unroll
      for (int i = 0; i < 2; ++i)
#pragma unroll
        for (int j = 0; j < 8; ++j)
          acc2[i][j] = __builtin_amdgcn_mfma_f32_16x16x32_bf16(af[i], bfr[j], acc2[i][j], 0, 0, 0);
    }
    __syncthreads();
  }

  // ---- phase 3: lg = relu(acc2) @ W3 via swizzled LDS bounce ----
  f32x4 acc3[4];
#pragma unroll
  for (int j = 0; j < 4; ++j) acc3[j] = z;

#pragma unroll
  for (int kk = 0; kk < 4; ++kk) {
    if (wc == (kk >> 1)) {
#pragma unroll
      for (int i = 0; i < 2; ++i)
#pragma unroll
        for (int j4 = 0; j4 < 4; ++j4) {
          int j = (kk & 1) * 4 + j4;
#pragma unroll
          for (int r = 0; r < 4; ++r) {
            int row = wr * 32 + i * 16 + lk * 4 + r;
            int c   = j4 * 16 + l15;
            quad[(row * 64 + c) ^ ((row & 7) << 3)] = f2bf(fmaxf(acc2[i][j][r], 0.f));
          }
        }
    }
#pragma unroll
    for (int it = 0; it < 2; ++it) {
      int s = it * 256 + t;
      int col = s >> 3;
      int koff = ((s ^ (col & 7)) & 7) * 8;
      gload_lds16(W3t + (size_t)col * 256 + kk * 64 + koff, &w3s[(it * 256 + wid * 64) * 8]);
    }
    __syncthreads();
    bf16x8 af2, bfr2[4];
#pragma unroll
    for (int ks = 0; ks < 2; ++ks) {
#pragma unroll
      for (int j2 = 0; j2 < 4; ++j2) {
        int col = j2 * 16 + l15;
        bfr2[j2] = *(const bf16x8*)&w3s[(col * 64 + ks * 32 + lk * 8) ^ ((col & 7) << 3)];
      }
      {
        int row = wid * 16 + l15;
        af2 = *(const bf16x8*)&quad[(row * 64 + ks * 32 + lk * 8) ^ ((row & 7) << 3)];
      }
#pragma unroll
      for (int j2 = 0; j2 < 4; ++j2)
        acc3[j2] = __builtin_amdgcn_mfma_f32_16x16x32_bf16(af2, bfr2[j2], acc3[j2], 0, 0, 0);
    }
    __syncthreads();
  }

#pragma unroll
  for (int j2 = 0; j2 < 4; ++j2) {
    int col = j2 * 16 + l15;
#pragma unroll
    for (int r = 0; r < 4; ++r) {
      int row = wid * 16 + lk * 4 + r;
      lg[(size_t)(bm * 64 + row) * 64 + col] = acc3[j2][r];
    }
  }
}

// ================= fused topk + soft-k-medoid per ppr row =================
// R12/R13 structure; scan phase upgraded:
//  - 2-deep pipeline of 8-load half-batches: issue nxt[8] BEFORE consuming
//    cur[8] -> in-flight never drains to zero (vs R13's 16->0 sawtooth).
//    Staging VGPR unchanged (2x8 f32x4 = 64).
//  - 4 independent sum accumulators: per-batch serial add chain 64 -> 16.
//    fp32 association change is ~1e-5 relative on rsum, far below the 2%
//    harness threshold (absmax pinned at 32 = bf16-MLP error for 12 rounds).
__global__ __launch_bounds__(256) void topk_medoid(const float* __restrict__ ppr,
                                                   const float* __restrict__ lg,
                                                   float* __restrict__ out) {
  __shared__ alignas(16) char smem[13312];
  float* cvals   = (float*)smem;              // [1024] (phase 1-2)
  int*   cidx    = (int*)(smem + 4096);       // [1024] (phase 1-2)
  float* xk      = (float*)smem;              // [32][65] (phase 3, aliases cands)
  float* l2m     = (float*)(smem + 8448);     // [32][33]
  float* vals    = (float*)(smem + 12672);    // [32]
  int*   idxs    = (int*)(smem + 12800);      // [32] (also fallback's sel)
  float* dist    = (float*)(smem + 12928);    // [32]
  float* wgt     = (float*)(smem + 13056);    // [32]
  float* partial = (float*)(smem + 13184);    // [4]
  int*   cnt     = (int*)(smem + 13200);      // [1]
  float* rsum    = (float*)(smem + 13204);    // [1]

  const int b = blockIdx.x, t = threadIdx.x;
  const int lane = t & 63, wid = t >> 6;
  const float* row = ppr + (size_t)b * 65536;
  const f32x4* rp = (const f32x4*)row;        // 16384 f32x4
  const float T0 = 0.997f;

  if (t == 0) *cnt = 0;
  __syncthreads();

  // ---- phase 1: scan, 2-deep pipelined half-batches of 8 ----
  float sum0 = 0.f, sum1 = 0.f, sum2 = 0.f, sum3 = 0.f;
  f32x4 cur[8], nxt[8];
#pragma unroll
  for (int i = 0; i < 8; ++i) cur[i] = ldnt(rp + i * 256 + t);

#pragma unroll 1
  for (int mb = 0; mb < 8; ++mb) {
    if (mb < 7) {
#pragma unroll
      for (int i = 0; i < 8; ++i) nxt[i] = ldnt(rp + ((mb + 1) * 8 + i) * 256 + t);
    }
#pragma unroll
    for (int i = 0; i < 8; ++i) {
      f32x4 x = cur[i];
      sum0 += x[0]; sum1 += x[1]; sum2 += x[2]; sum3 += x[3];
      float mx = fmaxf(fmaxf(x[0], x[1]), fmaxf(x[2], x[3]));
      if (mx > T0) {
        int fb = ((mb * 8 + i) * 256 + t) * 4;
#pragma unroll
        for (int j = 0; j < 4; ++j) {
          if (x[j] > T0) {
            int p = atomicAdd(cnt, 1);
            if (p < 1024) { cvals[p] = x[j]; cidx[p] = fb + j; }
          }
        }
      }
    }
    if (mb < 7) {
#pragma unroll
      for (int i = 0; i < 8; ++i) cur[i] = nxt[i];
    }
  }
  float sum = (sum0 + sum1) + (sum2 + sum3);
#pragma unroll
  for (int off = 32; off > 0; off >>= 1) sum += __shfl_down(sum, off);
  if (lane == 0) partial[wid] = sum;
  __syncthreads();

  // ---- phase 2: extraction ----
  const int ncand = *cnt;
  const int n = ncand < 1024 ? ncand : 1024;
  if (t == 0) *rsum = (partial[0] + partial[1]) + (partial[2] + partial[3]);

  if (n >= 32 && ncand <= 1024) {
    // parallel rank-select: rank(p) = #{q strictly better}; rank<32 wins.
    for (int p = t; p < n; p += 256) {
      float v = cvals[p];
      int id = cidx[p];
      int rank = 0;
      for (int q = 0; q < n; ++q) {
        float vq = cvals[q];
        int   iq = cidx[q];
        rank += (vq > v || (vq == v && iq < id)) ? 1 : 0;
      }
      if (rank < 32) { vals[rank] = v; idxs[rank] = id; }
    }
  } else if (wid == 0) {
    // exact fallback (never taken for uniform data)
    for (int r = 0; r < 32; ++r) {
      float bv = -__builtin_inff();
      int bi = 0x7fffffff;
      for (int p = lane; p < 65536; p += 64) {
        float xv = row[p];
        bool skip = false;
        for (int q = 0; q < r; ++q) skip = skip || (idxs[q] == p);
        if (!skip && (xv > bv || (xv == bv && p < bi))) { bv = xv; bi = p; }
      }
#pragma unroll
      for (int off = 32; off > 0; off >>= 1) {
        float ov = __shfl_down(bv, off);
        int   oi = __shfl_down(bi, off);
        if (ov > bv || (ov == bv && oi < bi)) { bv = ov; bi = oi; }
      }
      if (lane == 0) { vals[r] = bv; idxs[r] = bi; }
    }
  }
  __syncthreads();

  // ---- phase 3: medoid on own result ----
  const float rs_b = *rsum;
#pragma unroll
  for (int j = 0; j < 8; ++j) {
    int s = j * 256 + t;
    int r = s >> 6, c = s & 63;
    xk[r * 65 + c] = lg[(size_t)idxs[r] * 64 + c];
  }
  __syncthreads();
#pragma unroll
  for (int j = 0; j < 4; ++j) {
    int p = j * 256 + t;
    int c = p >> 5, m = p & 31;
    float d = 0.f;
#pragma unroll
    for (int ch = 0; ch < 64; ++ch) {
      float df = xk[c * 65 + ch] - xk[m * 65 + ch];
      d += df * df;
    }
    l2m[c * 33 + m] = sqrtf(d + 1e-12f);
  }
  __syncthreads();
  if (t < 32) {
    float d = 0.f;
#pragma unroll
    for (int m = 0; m < 32; ++m) d += vals[m] * l2m[t * 33 + m];
    if (vals[t] == 0.f) d = 3.402823466e+38f;
    dist[t] = d;
  }
  __syncthreads();
  if (t == 0) {
    float mx = -3.402823466e+38f;
    for (int c = 0; c < 32; ++c) mx = fmaxf(mx, -dist[c]);
    float s = 0.f;
    for (int c = 0; c < 32; ++c) { float e = expf(-dist[c] - mx); wgt[c] = e; s += e; }
    float s2 = 0.f;
    for (int c = 0; c < 32; ++c) { wgt[c] = wgt[c] / s * vals[c]; s2 += wgt[c]; }
    float inv = 1.f / s2;
    for (int c = 0; c < 32; ++c) wgt[c] *= inv;
  }
  __syncthreads();
  if (t < 64) {
    float o = 0.f;
#pragma unroll
    for (int k = 0; k < 32; ++k) o += wgt[k] * xk[k * 65 + t];
    out[(size_t)b * 64 + t] = rs_b * o;
  }
}

// ---------------- launch ----------------
extern "C" void kernel_launch(void* const* d_in, const int* in_sizes, int n_in,
                              void* d_out, int out_size, void* d_ws, size_t ws_size,
                              hipStream_t stream) {
  const float* X   = (const float*)d_in[0];
  const float* ppr = (const float*)d_in[1];
  const float* W1  = (const float*)d_in[2];
  const float* W2  = (const float*)d_in[3];
  const float* W3  = (const float*)d_in[4];
  float* out = (float*)d_out;
  char* ws = (char*)d_ws;

  u16*  w1t = (u16*)(ws + 0);                    // 256x512 bf16
  u16*  w2t = (u16*)(ws + 262144);               // 256x256 bf16
  u16*  w3t = (u16*)(ws + 393216);               // 64x256 bf16
  float* lg = (float*)(ws + 458752);             // 65536x64 fp32

  (void)in_sizes; (void)n_in; (void)out_size; (void)ws_size;

  conv_weights<<<832, 256, 0, stream>>>(W1, W2, W3, w1t, w2t, w3t);
  mlp_kernel<<<1024, 256, 0, stream>>>(X, w1t, w2t, w3t, lg);
  topk_medoid<<<2048, 256, 0, stream>>>(ppr, lg, out);
}